// Round 3
// baseline (311.993 us; speedup 1.0000x reference)
//
#include <hip/hip_runtime.h>
#include <hip/hip_bf16.h>

// Problem constants
#define NTOK 32768
#define CH   256
#define NEXP 16

typedef __attribute__((ext_vector_type(8)))  short short8;   // 8 x bf16 (4 VGPR)
typedef __attribute__((ext_vector_type(16))) float f32x16;   // MFMA 32x32 accumulator

#define MFMA32(a, b, c) __builtin_amdgcn_mfma_f32_32x32x16_bf16((a), (b), (c), 0, 0, 0)
#define BC8(v) __builtin_bit_cast(short8, (v))

// async global->LDS, 16B per lane; lds dst is wave-uniform base (+ lane*16 implicit)
#define GLD16(lds, g) __builtin_amdgcn_global_load_lds(                          \
    (const __attribute__((address_space(1))) unsigned int*)(g),                  \
    (__attribute__((address_space(3))) unsigned int*)(lds), 16, 0, 0)

// fp32 -> bf16 round-to-nearest-even
static __device__ __forceinline__ unsigned short f2bf(float f) {
  unsigned int u = __builtin_bit_cast(unsigned int, f);
  unsigned int r = (u + 0x7fffu + ((u >> 16) & 1u)) >> 16;
  return (unsigned short)r;
}
static __device__ __forceinline__ float bf2f(unsigned short h) {
  unsigned int u = ((unsigned int)h) << 16;
  return __builtin_bit_cast(float, u);
}

// ---------------------------------------------------------------------------
// Workspace layout (bytes):
//   [0,        16777216)  A_packed   N*C bf16, MFMA A-fragment order, per 64-tok tile
//   [16777216, 19005440)  W_packed   17*C*C bf16, MFMA B-fragment order
//   [19005440, 21102592)  combine    N*16 fp32
//   [21102592, 21168128)  frac_part  512*32 fp32
// ---------------------------------------------------------------------------

// Kernel 1: share_W (expert 16) + expert_W -> bf16 B-fragment order:
//   line (e, db, kb, lane) holds B[k = kb*16 + (lane>>5)*8 + j][d = db*32 + (lane&31)]
__global__ __launch_bounds__(256) void wconvert_kernel(
    const float* __restrict__ share_W, const float* __restrict__ expert_W,
    uint4* __restrict__ wp) {
  int g = blockIdx.x * 256 + threadIdx.x;   // 17*8192 lines
  int e = g >> 13;
  int r = g & 8191;
  int lane = r & 63;
  int kb = (r >> 6) & 15;
  int db = r >> 10;
  int d  = db * 32 + (lane & 31);
  int k0 = kb * 16 + ((lane >> 5) << 3);
  const float* src = (e < 16) ? (expert_W + (size_t)e * 65536) : share_W;
  unsigned int p[4];
#pragma unroll
  for (int j = 0; j < 4; j++) {
    float f0 = src[(size_t)(k0 + 2 * j) * 256 + d];
    float f1 = src[(size_t)(k0 + 2 * j + 1) * 256 + d];
    p[j] = (unsigned int)f2bf(f0) | ((unsigned int)f2bf(f1) << 16);
  }
  wp[g] = make_uint4(p[0], p[1], p[2], p[3]);
}

// Kernel 2 (v2): per 64-token block:
//  - A bf16 fragment-pack (unchanged from R1)
//  - logits via split-bf16 MFMA: route = h+l, gate_W = gh+gl, 4 effective passes
//    -> fp32-accurate logits with ZERO scalar dot products
//  - softmax/entropy/dynamic-k/rank fully in-lane (no shuffles)
__global__ __launch_bounds__(256, 2) void gate_kernel(
    const float* __restrict__ inputs, const float* __restrict__ conv_out,
    const float* __restrict__ domain_emb, const float* __restrict__ gate_W,
    const float* __restrict__ gate_b, const float* __restrict__ ln_gamma,
    const float* __restrict__ ln_beta, uint4* __restrict__ apack,
    float* __restrict__ combine, float* __restrict__ frac_part) {
  __shared__ __align__(16) unsigned short tile[16384];  // 32 KB: A-pack xor tile, then route h/l tiles
  __shared__ __align__(16) uint4 gwh[1024];             // 16 KB gate_W high-bf16 B-frags (cols>=16 zero)
  __shared__ __align__(16) uint4 gwl[1024];             // 16 KB gate_W low-bf16 B-frags
  __shared__ float logit_s[2][512];                     // 4 KB: [tile][tok*16+e]
  __shared__ float fsc[2][2][32][16];                   // 8 KB: [kind][tile][tok][e]
  int t = threadIdx.x, b = blockIdx.x;
  int w = t >> 6, l = t & 63;

  // ---- Phase 0a: gate_W h/l B-fragment staging ----
#pragma unroll
  for (int i = 0; i < 4; i++) {
    int sidx = i * 256 + t;          // 16 kb * 64 lanes
    int kb = sidx >> 6, lane = sidx & 63;
    int col = lane & 31;
    int k0 = kb * 16 + ((lane >> 5) << 3);
    unsigned int hw[4] = {0, 0, 0, 0}, lw[4] = {0, 0, 0, 0};
    if (col < 16) {
#pragma unroll
      for (int j = 0; j < 4; j++) {
        float f0 = gate_W[(k0 + 2 * j) * 16 + col];
        float f1 = gate_W[(k0 + 2 * j + 1) * 16 + col];
        unsigned short h0 = f2bf(f0), h1 = f2bf(f1);
        unsigned short l0 = f2bf(f0 - bf2f(h0)), l1 = f2bf(f1 - bf2f(h1));
        hw[j] = (unsigned int)h0 | ((unsigned int)h1 << 16);
        lw[j] = (unsigned int)l0 | ((unsigned int)l1 << 16);
      }
    }
    gwh[sidx] = make_uint4(hw[0], hw[1], hw[2], hw[3]);
    gwl[sidx] = make_uint4(lw[0], lw[1], lw[2], lw[3]);
  }

  // ---- Phase 0b: A-pack stage 1 (inputs -> bf16 xor-swizzled tile) ----
  for (int i = 0; i < 8; i++) {
    int idx = i * 256 + t;
    int row = idx >> 5;
    int j = idx & 31;
    const float4* src = (const float4*)(inputs + ((size_t)b * 64 + row) * 256 + j * 8);
    float4 f0 = src[0], f1 = src[1];
    unsigned int p0 = (unsigned int)f2bf(f0.x) | ((unsigned int)f2bf(f0.y) << 16);
    unsigned int p1 = (unsigned int)f2bf(f0.z) | ((unsigned int)f2bf(f0.w) << 16);
    unsigned int p2 = (unsigned int)f2bf(f1.x) | ((unsigned int)f2bf(f1.y) << 16);
    unsigned int p3 = (unsigned int)f2bf(f1.z) | ((unsigned int)f2bf(f1.w) << 16);
    int s = j ^ (row & 31);
    *(uint4*)(tile + (row * 32 + s) * 8) = make_uint4(p0, p1, p2, p3);
  }
  __syncthreads();

  // ---- Phase 1: A-pack stage 2 (tile -> apack) + LN compute (-> regs) ----
  for (int i = 0; i < 8; i++) {
    int L = i * 256 + t;
    int ll = L & 63;
    int mb = (L >> 6) & 1, kb = L >> 7;
    int row = mb * 32 + (ll & 31);
    int j = kb * 2 + (ll >> 5);
    int s = j ^ (row & 31);
    apack[(size_t)b * 2048 + L] = *(const uint4*)(tile + (row * 32 + s) * 8);
  }

  int lc = l * 4;
  float4 g4 = *(const float4*)(ln_gamma + lc);
  float4 be4 = *(const float4*)(ln_beta + lc);
  float4 de4 = *(const float4*)(domain_emb + lc);
  unsigned int hp0[16], hp1[16], lp0[16], lp1[16];
#pragma unroll 1
  for (int i = 0; i < 16; i++) {
    int n = b * 64 + w * 16 + i;
    float4 x = *(const float4*)(conv_out + (size_t)n * 256 + lc);
    float a1 = x.x + x.y + x.z + x.w;
    float a2 = x.x * x.x + x.y * x.y + x.z * x.z + x.w * x.w;
#pragma unroll
    for (int off = 1; off < 64; off <<= 1) {
      a1 += __shfl_xor(a1, off);
      a2 += __shfl_xor(a2, off);
    }
    float mu = a1 * (1.f / 256.f);
    float var = a2 * (1.f / 256.f) - mu * mu;
    float rstd = rsqrtf(var + 1e-5f);
    float rx = (x.x - mu) * rstd * g4.x + be4.x + de4.x;
    float ry = (x.y - mu) * rstd * g4.y + be4.y + de4.y;
    float rz = (x.z - mu) * rstd * g4.z + be4.z + de4.z;
    float rw = (x.w - mu) * rstd * g4.w + be4.w + de4.w;
    unsigned short h0 = f2bf(rx), h1 = f2bf(ry), h2 = f2bf(rz), h3 = f2bf(rw);
    hp0[i] = (unsigned int)h0 | ((unsigned int)h1 << 16);
    hp1[i] = (unsigned int)h2 | ((unsigned int)h3 << 16);
    unsigned short e0 = f2bf(rx - bf2f(h0)), e1 = f2bf(ry - bf2f(h1));
    unsigned short e2 = f2bf(rz - bf2f(h2)), e3 = f2bf(rw - bf2f(h3));
    lp0[i] = (unsigned int)e0 | ((unsigned int)e1 << 16);
    lp1[i] = (unsigned int)e2 | ((unsigned int)e3 << 16);
  }
  __syncthreads();  // all tile reads (stage 2) complete before overwrite

  // ---- Phase 2: write route_h tile (two 16 KB xor-swizzled 32-tok tiles) ----
  int jch = l >> 1;          // 16B chunk within row
  int half8 = (l & 1) * 4;   // ushort offset of 8B half
#pragma unroll
  for (int i = 0; i < 16; i++) {
    int n = w * 16 + i;
    int T = n >> 5, m = n & 31;
    unsigned short* dst = tile + T * 8192 + (m * 32 + (jch ^ m)) * 8 + half8;
    *(uint2*)dst = make_uint2(hp0[i], hp1[i]);
  }
  __syncthreads();

  // ---- Phase 3: MFMA pass on h ----
  f32x16 acc;
#pragma unroll
  for (int r = 0; r < 16; r++) acc[r] = 0.f;
  int m_ = l & 31, hf_ = l >> 5;
  if (w < 2) {
#pragma unroll
    for (int kb = 0; kb < 16; kb++) {
      int chunk = m_ * 32 + ((kb * 2 + hf_) ^ m_);
      short8 a = BC8(*(const uint4*)(tile + w * 8192 + chunk * 8));
      acc = MFMA32(a, BC8(gwh[kb * 64 + l]), acc);
      acc = MFMA32(a, BC8(gwl[kb * 64 + l]), acc);
    }
  }
  __syncthreads();

  // ---- Phase 4: write route_l tile ----
#pragma unroll
  for (int i = 0; i < 16; i++) {
    int n = w * 16 + i;
    int T = n >> 5, m = n & 31;
    unsigned short* dst = tile + T * 8192 + (m * 32 + (jch ^ m)) * 8 + half8;
    *(uint2*)dst = make_uint2(lp0[i], lp1[i]);
  }
  __syncthreads();

  // ---- Phase 5: MFMA pass on l, add bias, store logits ----
  if (w < 2) {
#pragma unroll
    for (int kb = 0; kb < 16; kb++) {
      int chunk = m_ * 32 + ((kb * 2 + hf_) ^ m_);
      short8 a = BC8(*(const uint4*)(tile + w * 8192 + chunk * 8));
      acc = MFMA32(a, BC8(gwh[kb * 64 + l]), acc);
      acc = MFMA32(a, BC8(gwl[kb * 64 + l]), acc);
    }
    int col = l & 31;
    if (col < 16) {
      float gb = gate_b[col];
#pragma unroll
      for (int r = 0; r < 16; r++) {
        int row = (r & 3) + ((r >> 2) << 3) + ((l >> 5) << 2);
        logit_s[w][row * 16 + col] = acc[r] + gb;
      }
    }
  }
  __syncthreads();

  // ---- Phase 6: per-token softmax/entropy/k/rank, fully in-lane ----
  if (w < 2 && l < 32) {
    int n = b * 64 + w * 32 + l;
    float lv[16];
#pragma unroll
    for (int q = 0; q < 4; q++)
      *(float4*)&lv[4 * q] = *(const float4*)&logit_s[w][l * 16 + 4 * q];
    float mx = lv[0];
#pragma unroll
    for (int e = 1; e < 16; e++) mx = fmaxf(mx, lv[e]);
    float p[16], sum = 0.f;
#pragma unroll
    for (int e = 0; e < 16; e++) { p[e] = expf(lv[e] - mx); sum += p[e]; }
    float inv = 1.f / sum;
    float wv[16], ent = 0.f;
#pragma unroll
    for (int e = 0; e < 16; e++) {
      wv[e] = p[e] * inv;
      ent -= wv[e] * logf(wv[e] + 1e-12f);
    }
    float kf = ceilf(1.f + ent * (15.f / 2.7725887f));
    int k = max(1, min(16, (int)kf));
    float cmb[16], selv[16];
#pragma unroll
    for (int e = 0; e < 16; e++) {
      int rk = 0;
#pragma unroll
      for (int j2 = 0; j2 < 16; j2++)
        rk += (int)((wv[j2] > wv[e]) || (wv[j2] == wv[e] && j2 < e));
      int sel = rk < k;
      cmb[e] = sel ? wv[e] : 0.f;
      selv[e] = sel ? 1.f : 0.f;
    }
#pragma unroll
    for (int q = 0; q < 4; q++) {
      *(float4*)&combine[(size_t)n * 16 + 4 * q] = *(float4*)&cmb[4 * q];
      *(float4*)&fsc[0][w][l][4 * q] = *(float4*)&selv[4 * q];
      *(float4*)&fsc[1][w][l][4 * q] = *(float4*)&wv[4 * q];
    }
  }
  __syncthreads();

  // ---- Phase 7: balance-loss partials ----
  if (t < 32) {
    int kind = t >> 4, e = t & 15;
    float ssum = 0.f;
    for (int T2 = 0; T2 < 2; T2++)
      for (int tok = 0; tok < 32; tok++)
        ssum += fsc[kind][T2][tok][e];
    frac_part[b * 32 + t] = ssum;
  }
}

// Kernel 3 (v4): 128 tok x 256 col per block, 8 waves, 1 block/CU.
// Wave w owns ALL 128 rows x one 32-col group (db = w): zero B duplication.
// Per slot (q-quarter x expert): ALL LDS reads (B-frags + previous slot's
// scale-add) come BEFORE the global_load_lds issue, so the prefetch stays in
// flight across the MFMA block and drains only at the end-of-slot barrier.
__global__ __launch_bounds__(512, 2) void moe_gemm_kernel(
    const uint4* __restrict__ apack, const uint4* __restrict__ wpack,
    const float* __restrict__ combine, const float* __restrict__ expert_b,
    const float* __restrict__ share_b, float* __restrict__ out) {
  extern __shared__ __align__(16) char smem[];
  uint4* atile  = (uint4*)smem;               // 4096 uint4 = 64 KB (128 tok x 256 k)
  uint4* btile0 = (uint4*)(smem + 65536);     // 32 KB
  uint4* btile1 = (uint4*)(smem + 98304);     // 32 KB
  float* wtile  = (float*)(smem + 131072);    // [e][row] 16*128 fp32 = 8 KB

  int t = threadIdx.x, b = blockIdx.x;
  int w = t >> 6, l = t & 63;
  int rowoff = (l >> 5) * 4;

  // ---- initial stages ----
#pragma unroll
  for (int i = 0; i < 8; i++) {
    int g = w * 8 + i;               // line g = kb*4 + mb
    int kb = g >> 2, mb = g & 3;
    GLD16(atile + g * 64,
          apack + ((size_t)(2 * b + (mb >> 1)) * 2048 + (size_t)(kb * 2 + (mb & 1)) * 64 + l));
  }
#pragma unroll
  for (int i = 0; i < 4; i++) {
    int g = w * 4 + i;               // line g = kbl*8 + db
    int kbl = g >> 3, db = g & 7;
    GLD16(btile0 + g * 64, wpack + ((size_t)db * 1024 + kbl * 64 + l));
  }
  {
    const float* cgp = combine + (size_t)b * 2048;
#pragma unroll
    for (int i = 0; i < 4; i++) {
      int idx = i * 512 + t;
      wtile[(idx & 15) * 128 + (idx >> 4)] = cgp[idx];
    }
  }

  f32x16 facc[4], tacc[4], zc;
#pragma unroll
  for (int r = 0; r < 16; r++) zc[r] = 0.f;
#pragma unroll
  for (int mi = 0; mi < 4; mi++)
#pragma unroll
    for (int r = 0; r < 16; r++) facc[mi][r] = 0.f;

  short8 areg[4][4];
  __syncthreads();   // A, B slot 0, wtile resident

  int s = 0;
  for (int q = 0; q < 4; q++) {
    // A-frags for this quarter: register-stationary across the 17 experts
#pragma unroll
    for (int kbl = 0; kbl < 4; kbl++)
#pragma unroll
      for (int mi = 0; mi < 4; mi++)
        areg[mi][kbl] = BC8(atile[((size_t)(q * 4 + kbl) * 4 + mi) * 64 + l]);

    for (int e = 0; e < 17; e++, s++) {
      const uint4* cb = (s & 1) ? btile1 : btile0;
      // 1) B-frags of current slot (LDS reads BEFORE any pending GLD)
      uint4 br[4];
#pragma unroll
      for (int kbl = 0; kbl < 4; kbl++) br[kbl] = cb[(size_t)(kbl * 8 + w) * 64 + l];

      // 2) fold previous slot's tacc into facc (wtile reads also pre-GLD)
      if (s > 0) {
        int ep = (s - 1) % 17;
        if (ep < 16) {
#pragma unroll
          for (int mi = 0; mi < 4; mi++)
#pragma unroll
            for (int rg = 0; rg < 4; rg++) {
              float4 w4 = *(const float4*)&wtile[ep * 128 + mi * 32 + 8 * rg + rowoff];
              facc[mi][rg * 4 + 0] += w4.x * tacc[mi][rg * 4 + 0];
              facc[mi][rg * 4 + 1] += w4.y * tacc[mi][rg * 4 + 1];
              facc[mi][rg * 4 + 2] += w4.z * tacc[mi][rg * 4 + 2];
              facc[mi][rg * 4 + 3] += w4.w * tacc[mi][rg * 4 + 3];
            }
        } else {
#pragma unroll
          for (int mi = 0; mi < 4; mi++)
#pragma unroll
            for (int r = 0; r < 16; r++) facc[mi][r] += tacc[mi][r];
        }
      }

      // 3) async prefetch of next slot's B (flies across the MFMA block)
      if (s < 67) {
        int sn = s + 1;
        int qn = sn / 17, en = sn - qn * 17;
        uint4* nb = (sn & 1) ? btile1 : btile0;
#pragma unroll
        for (int i = 0; i < 4; i++) {
          int g = w * 4 + i;
          int kbl = g >> 3, db = g & 7;
          GLD16(nb + g * 64,
                wpack + ((size_t)en * 8192 + (size_t)db * 1024 + (qn * 4 + kbl) * 64 + l));
        }
      }

      // 4) MFMA (zero-C init at kbl 0; 4 independent mi chains)
      {
        short8 b0 = BC8(br[0]);
        tacc[0] = MFMA32(areg[0][0], b0, zc);
        tacc[1] = MFMA32(areg[1][0], b0, zc);
        tacc[2] = MFMA32(areg[2][0], b0, zc);
        tacc[3] = MFMA32(areg[3][0], b0, zc);
      }
#pragma unroll
      for (int kbl = 1; kbl < 4; kbl++) {
        short8 bb = BC8(br[kbl]);
        tacc[0] = MFMA32(areg[0][kbl], bb, tacc[0]);
        tacc[1] = MFMA32(areg[1][kbl], bb, tacc[1]);
        tacc[2] = MFMA32(areg[2][kbl], bb, tacc[2]);
        tacc[3] = MFMA32(areg[3][kbl], bb, tacc[3]);
      }
      __syncthreads();  // drains GLD(s+1) + all waves done reading buf(s)
    }
  }
  // final fold: slot 67 was shared expert (ep = 16)
#pragma unroll
  for (int mi = 0; mi < 4; mi++)
#pragma unroll
    for (int r = 0; r < 16; r++) facc[mi][r] += tacc[mi][r];

  // ---- epilogue: bias terms + store ----
  int col = l & 31;
  int cg = w * 32 + col;
  float sb = share_b[cg];
#pragma unroll
  for (int e2 = 0; e2 < 16; e2++) {
    float eb = expert_b[e2 * 256 + cg];
#pragma unroll
    for (int mi = 0; mi < 4; mi++)
#pragma unroll
      for (int rg = 0; rg < 4; rg++) {
        float4 w4 = *(const float4*)&wtile[e2 * 128 + mi * 32 + 8 * rg + rowoff];
        facc[mi][rg * 4 + 0] += w4.x * eb;
        facc[mi][rg * 4 + 1] += w4.y * eb;
        facc[mi][rg * 4 + 2] += w4.z * eb;
        facc[mi][rg * 4 + 3] += w4.w * eb;
      }
  }
#pragma unroll
  for (int mi = 0; mi < 4; mi++)
#pragma unroll
    for (int r = 0; r < 16; r++) {
      int row = mi * 32 + (r & 3) + ((r >> 2) << 3) + rowoff;
      out[((size_t)b * 128 + row) * 256 + cg] = facc[mi][r] + sb;
    }
}

// Kernel 4: reduce balance-loss partials -> scalar at d_out[N*C]
__global__ __launch_bounds__(256) void finalize_kernel(
    const float* __restrict__ frac_part, float* __restrict__ loss_out) {
  __shared__ float acc[8][32];
  int t = threadIdx.x;
  int col = t & 31, seg = t >> 5;
  float s = 0.f;
  for (int i = seg; i < 512; i += 8) s += frac_part[i * 32 + col];
  acc[seg][col] = s;
  __syncthreads();
  if (t < 32) {
    float v = 0.f;
#pragma unroll
    for (int sg = 0; sg < 8; sg++) v += acc[sg][t];
    acc[0][t] = v;
  }
  __syncthreads();
  if (t == 0) {
    float loss = 0.f;
    for (int e = 0; e < 16; e++) {
      float ft = acc[0][e] * (1.f / 32768.f);
      float fp = acc[0][16 + e] * (1.f / 32768.f);
      loss += ft * fp;
    }
    loss_out[0] = loss * 16.f;
  }
}

extern "C" void kernel_launch(void* const* d_in, const int* in_sizes, int n_in,
                              void* d_out, int out_size, void* d_ws, size_t ws_size,
                              hipStream_t stream) {
  const float* inputs   = (const float*)d_in[0];
  const float* conv_out = (const float*)d_in[1];
  const float* demb     = (const float*)d_in[2];
  const float* share_W  = (const float*)d_in[3];
  const float* share_b  = (const float*)d_in[4];
  const float* gate_W   = (const float*)d_in[5];
  const float* gate_b   = (const float*)d_in[6];
  const float* expert_W = (const float*)d_in[7];
  const float* expert_b = (const float*)d_in[8];
  const float* ln_g     = (const float*)d_in[9];
  const float* ln_b     = (const float*)d_in[10];
  float* out = (float*)d_out;
  char* ws = (char*)d_ws;

  uint4* apack   = (uint4*)(ws);
  uint4* wpack   = (uint4*)(ws + 16777216);
  float* combine = (float*)(ws + 19005440);
  float* frac    = (float*)(ws + 21102592);

  hipFuncSetAttribute((const void*)moe_gemm_kernel,
                      hipFuncAttributeMaxDynamicSharedMemorySize, 139264);

  wconvert_kernel<<<dim3(544), dim3(256), 0, stream>>>(share_W, expert_W, wpack);
  gate_kernel<<<dim3(512), dim3(256), 0, stream>>>(inputs, conv_out, demb, gate_W,
                                                   gate_b, ln_g, ln_b, apack, combine, frac);
  moe_gemm_kernel<<<dim3(256), dim3(512), 139264, stream>>>(apack, wpack, combine,
                                                            expert_b, share_b, out);
  finalize_kernel<<<dim3(1), dim3(256), 0, stream>>>(frac, out + 8388608);
}